// Round 1
// baseline (128.697 us; speedup 1.0000x reference)
//
#include <hip/hip_runtime.h>
#include <math.h>

#define BINS 10
#define IGNORE_INDEX (-100)

__device__ __forceinline__ float safe_expf(float d) {
    // d = a - b where both could be -inf (then d = NaN); treat as exp(-inf)=0
    return (d != d || d == -INFINITY) ? 0.0f : __expf(d);
}

__global__ __launch_bounds__(64) void ghmc_init_counts(int* counts) {
    int t = threadIdx.x;
    if (t < BINS + 1) counts[t] = 0;
}

// One block per row: online logsumexp over C columns, then per-row stats.
__global__ __launch_bounds__(256) void ghmc_row_kernel(
    const float* __restrict__ y_pred,
    const int*   __restrict__ y_true,
    float*       __restrict__ logprob,
    int*         __restrict__ seg,
    int*         __restrict__ counts,
    int C)
{
    const int row = blockIdx.x;
    const float* rp = y_pred + (size_t)row * (size_t)C;
    const int tid = threadIdx.x;
    const int nthreads = blockDim.x;   // 256

    float m = -INFINITY;
    float s = 0.0f;

    const int n4 = C >> 2;
    const float4* rp4 = reinterpret_cast<const float4*>(rp);
    for (int i = tid; i < n4; i += nthreads) {
        float4 v = rp4[i];
        float vm = fmaxf(fmaxf(v.x, v.y), fmaxf(v.z, v.w));
        if (vm > m) {
            s *= safe_expf(m - vm);
            m = vm;
        }
        s += __expf(v.x - m) + __expf(v.y - m) + __expf(v.z - m) + __expf(v.w - m);
    }
    // tail if C % 4 != 0
    for (int i = (n4 << 2) + tid; i < C; i += nthreads) {
        float v = rp[i];
        if (v > m) { s *= safe_expf(m - v); m = v; }
        s += __expf(v - m);
    }

    // wave-64 butterfly combine of (m, s)
    #pragma unroll
    for (int off = 32; off >= 1; off >>= 1) {
        float om = __shfl_xor(m, off);
        float os = __shfl_xor(s, off);
        float nm = fmaxf(m, om);
        s = s * safe_expf(m - nm) + os * safe_expf(om - nm);
        m = nm;
    }

    __shared__ float sm[4], ss[4];
    const int wave = tid >> 6, lane = tid & 63;
    if (lane == 0) { sm[wave] = m; ss[wave] = s; }
    __syncthreads();

    if (tid == 0) {
        float M = sm[0], S = ss[0];
        #pragma unroll
        for (int w = 1; w < 4; ++w) {
            float om = sm[w], os = ss[w];
            float nm = fmaxf(M, om);
            S = S * safe_expf(M - nm) + os * safe_expf(om - nm);
            M = nm;
        }
        const int label = y_true[row];
        int idx = label < 0 ? 0 : (label >= C ? C - 1 : label);  // clip like reference
        float xt = rp[idx];
        float lp = xt - M - logf(S);
        logprob[row] = lp;

        float p = __expf(lp);
        float g = 1.0f - p;

        // searchsorted(edges, g, side='right') - 1, edges[i] = i/10 in fp32
        int bin = -1;
        #pragma unroll
        for (int i = 0; i <= BINS; ++i) {
            float edge = (float)i / (float)BINS;
            if (edge <= g) bin = i;
        }
        const bool valid = (label != IGNORE_INDEX);
        const bool in_range = (bin >= 0) && (bin < BINS) && valid;
        const int sg = in_range ? bin : BINS;
        seg[row] = sg;
        if (sg < BINS) atomicAdd(&counts[sg], 1);
    }
}

// Single block: num_labels, per-bin weights, deterministic weighted-loss reduction.
__global__ __launch_bounds__(256) void ghmc_finalize_kernel(
    const int*   __restrict__ y_true,
    const float* __restrict__ logprob,
    const int*   __restrict__ seg,
    const int*   __restrict__ counts,
    float*       __restrict__ out,
    int B)
{
    const int tid = threadIdx.x;
    const int wave = tid >> 6, lane = tid & 63;

    // num_labels = sum(y_true != IGNORE_INDEX)
    int nl = 0;
    for (int i = tid; i < B; i += blockDim.x)
        nl += (y_true[i] != IGNORE_INDEX) ? 1 : 0;
    #pragma unroll
    for (int off = 32; off >= 1; off >>= 1) nl += __shfl_xor(nl, off);

    __shared__ int snl[4];
    if (lane == 0) snl[wave] = nl;
    __syncthreads();

    __shared__ float wpb[BINS + 1];
    __shared__ float s_num_labels;
    if (tid == 0) {
        const int NL = snl[0] + snl[1] + snl[2] + snl[3];
        const float num_labels = (float)NL;
        s_num_labels = num_labels;
        int n = 0;
        #pragma unroll
        for (int i = 0; i < BINS; ++i) n += (counts[i] > 0) ? 1 : 0;
        const float nf = fmaxf((float)n, 1.0f);
        #pragma unroll
        for (int i = 0; i < BINS; ++i) {
            float w = (counts[i] > 0) ? (num_labels / (float)counts[i]) : 0.0f;
            wpb[i] = w / nf;
        }
        wpb[BINS] = 0.0f;  // overflow bin weight 0
    }
    __syncthreads();

    float acc = 0.0f;
    for (int i = tid; i < B; i += blockDim.x) {
        const int label = y_true[i];
        const bool valid = (label != IGNORE_INDEX);
        const float lp = valid ? logprob[i] : 0.0f;
        acc += -(wpb[seg[i]] * lp);
    }
    #pragma unroll
    for (int off = 32; off >= 1; off >>= 1) acc += __shfl_xor(acc, off);

    __shared__ float sacc[4];
    if (lane == 0) sacc[wave] = acc;
    __syncthreads();
    if (tid == 0) {
        float total = sacc[0] + sacc[1] + sacc[2] + sacc[3];
        out[0] = total / s_num_labels;
    }
}

extern "C" void kernel_launch(void* const* d_in, const int* in_sizes, int n_in,
                              void* d_out, int out_size, void* d_ws, size_t ws_size,
                              hipStream_t stream) {
    const float* y_pred = (const float*)d_in[0];
    const int*   y_true = (const int*)d_in[1];
    const int B = in_sizes[1];
    const int C = (int)(in_sizes[0] / (size_t)in_sizes[1]);
    float* out = (float*)d_out;

    char* ws = (char*)d_ws;
    int*   counts  = (int*)ws;                                // 16 ints (64 B)
    float* logprob = (float*)(ws + 64);                       // B floats
    int*   seg     = (int*)(ws + 64 + (size_t)B * sizeof(float)); // B ints

    ghmc_init_counts<<<1, 64, 0, stream>>>(counts);
    ghmc_row_kernel<<<B, 256, 0, stream>>>(y_pred, y_true, logprob, seg, counts, C);
    ghmc_finalize_kernel<<<1, 256, 0, stream>>>(y_true, logprob, seg, counts, out, B);
}

// Round 3
// 91.308 us; speedup vs baseline: 1.4095x; 1.4095x over previous
//
#include <hip/hip_runtime.h>
#include <math.h>

#define BINS 10
#define IGNORE_INDEX (-100)

typedef float fvec4 __attribute__((ext_vector_type(4)));

__device__ __forceinline__ float safe_expf(float d) {
    // d may be NaN (-inf - -inf) or -inf; both mean "scale by 0"
    return (d != d || d == -INFINITY) ? 0.0f : __expf(d);
}

__device__ __forceinline__ void acc4(fvec4 v, float& m, float& s) {
    float vm = fmaxf(fmaxf(v.x, v.y), fmaxf(v.z, v.w));
    if (vm > m) { s *= safe_expf(m - vm); m = vm; }
    s += (__expf(v.x - m) + __expf(v.y - m)) + (__expf(v.z - m) + __expf(v.w - m));
}

// One block per row: online logsumexp over C columns, then per-row stats.
__global__ __launch_bounds__(256) void ghmc_row_kernel(
    const float* __restrict__ y_pred,
    const int*   __restrict__ y_true,
    float*       __restrict__ logprob,
    int*         __restrict__ seg,
    int C)
{
    const int row = blockIdx.x;
    const float* rp = y_pred + (size_t)row * (size_t)C;
    const int tid = threadIdx.x;
    const int nthreads = blockDim.x;   // 256

    // Prefetch the true-class logit EARLY so its HBM latency hides under the
    // streaming loop (all lanes load the same address -> broadcast).
    const int label = y_true[row];
    const int cidx  = label < 0 ? 0 : (label >= C ? C - 1 : label);
    const float xt  = rp[cidx];

    float m0 = -INFINITY, s0 = 0.0f;
    float m1 = -INFINITY, s1 = 0.0f;

    const int n4 = C >> 2;
    const fvec4* rp4 = reinterpret_cast<const fvec4*>(rp);

    int i = tid;
    // 2-way unrolled: two independent accumulator pairs -> 2 loads in flight.
    for (; i + nthreads < n4; i += 2 * nthreads) {
        fvec4 a = __builtin_nontemporal_load(&rp4[i]);
        fvec4 b = __builtin_nontemporal_load(&rp4[i + nthreads]);
        acc4(a, m0, s0);
        acc4(b, m1, s1);
    }
    for (; i < n4; i += nthreads) {
        fvec4 a = __builtin_nontemporal_load(&rp4[i]);
        acc4(a, m0, s0);
    }
    // scalar tail if C % 4 != 0
    for (int j = (n4 << 2) + tid; j < C; j += nthreads) {
        float v = rp[j];
        if (v > m0) { s0 *= safe_expf(m0 - v); m0 = v; }
        s0 += __expf(v - m0);
    }

    // merge the two accumulators
    {
        float nm = fmaxf(m0, m1);
        s0 = s0 * safe_expf(m0 - nm) + s1 * safe_expf(m1 - nm);
        m0 = nm;
    }

    // wave-64 butterfly combine of (m, s)
    #pragma unroll
    for (int off = 32; off >= 1; off >>= 1) {
        float om = __shfl_xor(m0, off);
        float os = __shfl_xor(s0, off);
        float nm = fmaxf(m0, om);
        s0 = s0 * safe_expf(m0 - nm) + os * safe_expf(om - nm);
        m0 = nm;
    }

    __shared__ float sm[4], ss[4];
    const int wave = tid >> 6, lane = tid & 63;
    if (lane == 0) { sm[wave] = m0; ss[wave] = s0; }
    __syncthreads();

    if (tid == 0) {
        float M = sm[0], S = ss[0];
        #pragma unroll
        for (int w = 1; w < 4; ++w) {
            float om = sm[w], os = ss[w];
            float nm = fmaxf(M, om);
            S = S * safe_expf(M - nm) + os * safe_expf(om - nm);
            M = nm;
        }
        float lp = xt - M - logf(S);
        logprob[row] = lp;

        float p = __expf(lp);
        float g = 1.0f - p;

        // searchsorted(edges, g, side='right') - 1, edges[i] = i/10 in fp32
        int bin = -1;
        #pragma unroll
        for (int k = 0; k <= BINS; ++k) {
            float edge = (float)k / (float)BINS;
            if (edge <= g) bin = k;
        }
        const bool valid = (label != IGNORE_INDEX);
        const bool in_range = (bin >= 0) && (bin < BINS) && valid;
        seg[row] = in_range ? bin : BINS;
    }
}

// Single block: histogram from seg, num_labels, weights, weighted-loss sum.
__global__ __launch_bounds__(1024) void ghmc_finalize_kernel(
    const int*   __restrict__ y_true,
    const float* __restrict__ logprob,
    const int*   __restrict__ seg,
    float*       __restrict__ out,
    int B)
{
    const int tid = threadIdx.x;
    const int wave = tid >> 6, lane = tid & 63;
    const int NW = 16;  // 1024 / 64

    __shared__ int s_counts[BINS + 1];
    if (tid < BINS + 1) s_counts[tid] = 0;
    __syncthreads();

    int nl = 0;
    for (int i = tid; i < B; i += blockDim.x) {
        const int label = y_true[i];
        nl += (label != IGNORE_INDEX) ? 1 : 0;
        const int sg = seg[i];
        if (sg < BINS) atomicAdd(&s_counts[sg], 1);
    }
    #pragma unroll
    for (int off = 32; off >= 1; off >>= 1) nl += __shfl_xor(nl, off);

    __shared__ int snl[NW];
    if (lane == 0) snl[wave] = nl;
    __syncthreads();

    __shared__ float wpb[BINS + 1];
    __shared__ float s_num_labels;
    if (tid == 0) {
        int NL = 0;
        #pragma unroll
        for (int w = 0; w < NW; ++w) NL += snl[w];
        const float num_labels = (float)NL;
        s_num_labels = num_labels;
        int n = 0;
        #pragma unroll
        for (int k = 0; k < BINS; ++k) n += (s_counts[k] > 0) ? 1 : 0;
        const float nf = fmaxf((float)n, 1.0f);
        #pragma unroll
        for (int k = 0; k < BINS; ++k) {
            float w = (s_counts[k] > 0) ? (num_labels / (float)s_counts[k]) : 0.0f;
            wpb[k] = w / nf;
        }
        wpb[BINS] = 0.0f;  // overflow bin weight 0
    }
    __syncthreads();

    float acc = 0.0f;
    for (int i = tid; i < B; i += blockDim.x) {
        const int label = y_true[i];
        const bool valid = (label != IGNORE_INDEX);
        const float lp = valid ? logprob[i] : 0.0f;
        acc += -(wpb[seg[i]] * lp);
    }
    #pragma unroll
    for (int off = 32; off >= 1; off >>= 1) acc += __shfl_xor(acc, off);

    __shared__ float sacc[NW];
    if (lane == 0) sacc[wave] = acc;
    __syncthreads();
    if (tid == 0) {
        float total = 0.0f;
        #pragma unroll
        for (int w = 0; w < NW; ++w) total += sacc[w];
        out[0] = total / s_num_labels;
    }
}

extern "C" void kernel_launch(void* const* d_in, const int* in_sizes, int n_in,
                              void* d_out, int out_size, void* d_ws, size_t ws_size,
                              hipStream_t stream) {
    const float* y_pred = (const float*)d_in[0];
    const int*   y_true = (const int*)d_in[1];
    const int B = in_sizes[1];
    const int C = (int)(in_sizes[0] / (size_t)in_sizes[1]);
    float* out = (float*)d_out;

    char* ws = (char*)d_ws;
    float* logprob = (float*)ws;                              // B floats
    int*   seg     = (int*)(ws + (size_t)B * sizeof(float));  // B ints

    ghmc_row_kernel<<<B, 256, 0, stream>>>(y_pred, y_true, logprob, seg, C);
    ghmc_finalize_kernel<<<1, 1024, 0, stream>>>(y_true, logprob, seg, out, B);
}